// Round 16
// baseline (26.246 us; speedup 1.0000x reference)
//
#include <hip/hip_runtime.h>
#include <stdint.h>

#define BB 512
#define NN 8192
#define KK 16
#define HH 16

typedef _Float16 f16;
typedef _Float16 f16x4 __attribute__((ext_vector_type(4)));
typedef float f32x4 __attribute__((ext_vector_type(4)));

// ---------------------------------------------------------------------------
// Kernel 1: pack signs of x (+-1) into transposed-word bitmask.
// xpT[j*16+w] bit i = (x[(w*32+i)*N+j] > 0).  512 KB, L2-resident.
// 256 blocks x 512 thr: coalesced x reads, LDS-staged contiguous 2KB write.
// ---------------------------------------------------------------------------
__global__ __launch_bounds__(512) void pack_kernel(const float* __restrict__ x,
                                                   uint32_t* __restrict__ xpT) {
    __shared__ uint32_t pstage[32 * 17];
    const int tid = threadIdx.x;
    const int j0  = blockIdx.x * 32;
    const int jl  = tid & 31;   // 32 consecutive j -> 128B coalesced reads
    const int wq  = tid >> 5;   // word group 0..15
    uint32_t word = 0u;
#pragma unroll
    for (int i = 0; i < 32; ++i)
        word |= (x[(size_t)(wq * 32 + i) * NN + j0 + jl] > 0.0f ? 1u : 0u) << i;
    pstage[jl * 17 + wq] = word;
    __syncthreads();
    xpT[(size_t)j0 * 16 + tid] = pstage[(tid >> 4) * 17 + (tid & 15)];
}

// ---------------------------------------------------------------------------
// Kernel 2 (R10 champion geometry + 4-deep MFMA batching):
// grid (1024,2) = 2048 blocks -> 2 generations at 4 blocks/CU.
// Block = 8n x 256b, 512 thr = 8 waves; wave = 1 n (no prologue barriers).
// CHANGE vs R10: per 4-tile group, build all 4 B-frags first, then issue
// 4 MFMAs into 4 SEPARATE accumulators, then 4 relu-dots -- breaks the
// per-tile MFMA->VALU serial chain the compiler was emitting (VGPR=28),
// giving a 4-deep independent burst per wave.  zbuf rows padded to 6
// (kills the 4-way bank conflict seen in R10: 987K -> ~300K).  Dense
// sigmoid pass per 4-tile group unchanged.  Output transpose fused via
// tile[256][12]; single __syncthreads before the store.
// LDS: wbuf 5K + zbuf 12K + tile 12K = 29.6KB -> 4 blocks/CU, 8 waves/SIMD.
// ---------------------------------------------------------------------------
__global__ __launch_bounds__(512, 8) void mfma_kernel(
    const uint32_t* __restrict__ xpT, const float* __restrict__ W1,
    const int* __restrict__ neighs, const float* __restrict__ b1,
    const float* __restrict__ W2, const float* __restrict__ b2,
    float* __restrict__ out) {
    __shared__ __align__(16) uint32_t wbuf[8][8 * 20];  // [wave][w*20+k]
    __shared__ __align__(16) float zbuf[8][64][6];      // padded rows
    __shared__ __align__(16) float tile[256 * 12];      // [b_local][n_local]

    const int tid = threadIdx.x;
    const int wv  = tid >> 6;        // 0..7  (= n_local)
    const int l   = tid & 63;
    const int l15 = l & 15;
    const int lg  = l >> 4;          // 0..3
    const int n0  = blockIdx.x * 8;
    const int b0  = blockIdx.y * 256;
    const int w0  = blockIdx.y * 8;  // word base for this b-half

    const int n = n0 + wv;

    // ---- issue all independent global loads up front (no barriers) ----
    const int j = neighs[n * KK + l15];                  // 64B broadcast
    const uint2 g = *(const uint2*)&xpT[(size_t)j * 16 + w0 + lg * 2];
    const float* W1n = W1 + (size_t)n * (KK * HH) + lg * 4 * HH + l15;
    const float a0 = W1n[0 * HH];
    const float a1 = W1n[1 * HH];
    const float a2 = W1n[2 * HH];
    const float a3 = W1n[3 * HH];
    const float4 b1v = *(const float4*)(b1 + (size_t)n * HH + lg * 4);
    const float4 w2v = *(const float4*)(W2 + (size_t)n * HH + lg * 4);
    const float b2n = b2[n];

    const f16x4 a = {(f16)a0, (f16)a1, (f16)a2, (f16)a3};
    const f32x4 cinit = {b1v.x, b1v.y, b1v.z, b1v.w};

    // ---- stage sign words to wave-private LDS (lgkmcnt-ordered) ----
    wbuf[wv][(2 * lg) * 20 + l15]     = g.x;
    wbuf[wv][(2 * lg + 1) * 20 + l15] = g.y;

#pragma unroll
    for (int g4 = 0; g4 < 4; ++g4) {   // 4 groups x 4 tiles of 16 b
        // ---- build all 4 B-frags of this group first ----
        f16x4 bfr[4];
#pragma unroll
        for (int t = 0; t < 4; ++t) {
            const int tb = g4 * 4 + t;
            const int wg = tb >> 1;
            const uint4 wk = *(const uint4*)&wbuf[wv][wg * 20 + lg * 4];
            const int pos = (tb & 1) * 16 + l15;  // bit index within word
            // bit=1 -> +1.0f16 (0x3C00), bit=0 -> -1.0f16 (0xBC00)
            const uint32_t d0 = 0xBC00BC00u ^ (((wk.x >> pos) & 1u) << 15) ^
                                ((wk.y >> pos) << 31);
            const uint32_t d1 = 0xBC00BC00u ^ (((wk.z >> pos) & 1u) << 15) ^
                                ((wk.w >> pos) << 31);
            uint2 bdu; bdu.x = d0; bdu.y = d1;
            bfr[t] = __builtin_bit_cast(f16x4, bdu);
        }

        // ---- 4 back-to-back MFMAs, independent accumulators ----
        f32x4 acc0 = __builtin_amdgcn_mfma_f32_16x16x16f16(a, bfr[0], cinit, 0, 0, 0);
        f32x4 acc1 = __builtin_amdgcn_mfma_f32_16x16x16f16(a, bfr[1], cinit, 0, 0, 0);
        f32x4 acc2 = __builtin_amdgcn_mfma_f32_16x16x16f16(a, bfr[2], cinit, 0, 0, 0);
        f32x4 acc3 = __builtin_amdgcn_mfma_f32_16x16x16f16(a, bfr[3], cinit, 0, 0, 0);

        // ---- 4 relu-dots (split-tree chains), write to padded zbuf ----
#pragma unroll
        for (int t = 0; t < 4; ++t) {
            const f32x4 acc = (t == 0) ? acc0 : (t == 1) ? acc1
                              : (t == 2) ? acc2 : acc3;
            const float p0 = fmaf(fmaxf(acc[0], 0.f), w2v.x,
                                  fmaxf(acc[1], 0.f) * w2v.y);
            const float p1 = fmaf(fmaxf(acc[2], 0.f), w2v.z,
                                  fmaxf(acc[3], 0.f) * w2v.w);
            zbuf[wv][t * 16 + l15][lg] = p0 + p1;
        }

        // ---- dense pass: 64 lanes = 64 outputs of this 4-tile group ----
        const float z = (zbuf[wv][l][0] + zbuf[wv][l][1]) +
                        (zbuf[wv][l][2] + zbuf[wv][l][3]) + b2n;
        const float r = __builtin_amdgcn_rcpf(1.0f + __expf(-z));
        tile[(g4 * 64 + l) * 12 + wv] = r;
    }
    __syncthreads();

    // stores: 2 lanes cover one 32B half-row of out[b][n0..n0+7]
    const int row = tid >> 1;
    const int c   = (tid & 1) * 4;
    const float4 v = *(const float4*)&tile[row * 12 + c];
    *(float4*)(out + (size_t)(b0 + row) * NN + n0 + c) = v;
}

// ---------------------------------------------------------------------------
// Fallback scalar kernel (only if workspace is too small).
// ---------------------------------------------------------------------------
__global__ __launch_bounds__(512) void scalar_kernel(
    const float* __restrict__ x, const int* __restrict__ neighs,
    const float* __restrict__ W1, const float* __restrict__ b1,
    const float* __restrict__ W2, const float* __restrict__ b2,
    float* __restrict__ outp) {
    const int n = blockIdx.x;
    const int b = threadIdx.x;
    const int* nb = neighs + n * KK;
    const float* W1n = W1 + (size_t)n * KK * HH;
    const float* b1n = b1 + (size_t)n * HH;
    const float* W2n = W2 + (size_t)n * HH;

    float s[KK];
#pragma unroll
    for (int k = 0; k < KK; ++k) s[k] = x[(size_t)b * NN + nb[k]];

    float acc[HH];
#pragma unroll
    for (int h = 0; h < HH; ++h) acc[h] = b1n[h];
#pragma unroll
    for (int k = 0; k < KK; ++k)
#pragma unroll
        for (int h = 0; h < HH; ++h)
            acc[h] = fmaf(s[k], W1n[k * HH + h], acc[h]);

    float z = b2[n];
#pragma unroll
    for (int h = 0; h < HH; ++h)
        z = fmaf(fmaxf(acc[h], 0.0f), W2n[h], z);
    outp[(size_t)b * NN + n] = 1.0f / (1.0f + __expf(-z));
}

extern "C" void kernel_launch(void* const* d_in, const int* in_sizes, int n_in,
                              void* d_out, int out_size, void* d_ws, size_t ws_size,
                              hipStream_t stream) {
    const float* x      = (const float*)d_in[0];
    const int*   neighs = (const int*)d_in[1];
    const float* W1     = (const float*)d_in[2];
    const float* b1     = (const float*)d_in[3];
    const float* W2     = (const float*)d_in[4];
    const float* b2     = (const float*)d_in[5];
    float* out = (float*)d_out;

    const size_t pack_bytes = (size_t)NN * 16 * sizeof(uint32_t);  // 512 KB

    if (ws_size >= pack_bytes) {
        uint32_t* xpT = (uint32_t*)d_ws;
        pack_kernel<<<NN / 32, 512, 0, stream>>>(x, xpT);
        mfma_kernel<<<dim3(NN / 8, BB / 256), 512, 0, stream>>>(
            xpT, W1, neighs, b1, W2, b2, out);
    } else {
        scalar_kernel<<<NN, BB, 0, stream>>>(x, neighs, W1, b1, W2, b2, out);
    }
}